// Round 7
// baseline (1234.538 us; speedup 1.0000x reference)
//
#include <hip/hip_runtime.h>
#include <hip/hip_fp16.h>
#include <math.h>

#define NN    4096
#define NITER 20
#define TPB   1024
#define NBLK  256     // == CU count; 1 block/CU (forced by LDS)
#define ROWS  16      // rows of E per block

// ---- dynamic LDS layout ----
#define EH_OFF    0        // __half Eh[16][4096]           = 131072 B
#define VB_OFF    131072   // float  vbuf[4096]             =  16384 B
#define U_OFF     147456   // double u_lds[16]              =    128 B
#define UF_OFF    147584   // float  uf_lds[16]             =     64 B
#define SMEM_BYTES 147648
// final phase aliases lv[4096] (double, 32 KB) onto Eh space.

// Native ext-vector types: required for inline-asm "v" constraints.
typedef float    vf4 __attribute__((ext_vector_type(4)));
typedef unsigned vu4 __attribute__((ext_vector_type(4)));

// exp of a double argument with fp32 exp + first-order fp64 correction.
__device__ __forceinline__ double exp_hi(double x) {
    float xf = (float)x;
    double dl = x - (double)xf;
    double e = (double)expf(xf);
    return fma(e, dl, e);
}

union U8 { ushort4 s; __half2 h[2]; };   // 8 B = 4 halves
union DF { double d[2]; vf4 f; };        // fp64 pair <-> 16B asm payload

// ---- device-scope PLAIN memory ops (sc1: bypass L1+per-XCD L2, serve at LLC).
__device__ __forceinline__ void st_dev_u32(unsigned* p, unsigned v) {
    asm volatile("global_store_dword %0, %1, off sc1" :: "v"(p), "v"(v) : "memory");
}
__device__ __forceinline__ vu4 ld_dev_u32x4(const unsigned* p) {
    vu4 r;
    asm volatile("global_load_dwordx4 %0, %1, off sc1\n\ts_waitcnt vmcnt(0)"
                 : "=v"(r) : "v"(p) : "memory");
    return r;
}
__device__ __forceinline__ vf4 ld_dev_f4(const float* p) {
    vf4 r;
    asm volatile("global_load_dwordx4 %0, %1, off sc1\n\ts_waitcnt vmcnt(0)"
                 : "=v"(r) : "v"(p) : "memory");
    return r;
}
__device__ __forceinline__ void ld2_dev_d2(const double* p0, const double* p1,
                                           vf4& x, vf4& y) {
    asm volatile(
        "global_load_dwordx4 %0, %2, off sc1\n\t"
        "global_load_dwordx4 %1, %3, off sc1\n\t"
        "s_waitcnt vmcnt(0)"
        : "=&v"(x), "=&v"(y)
        : "v"(p0), "v"(p1) : "memory");
}

// ---- RMW-free "all-check" grid barrier (round-6, measured ~5-6 us incl. skew).
// Each block STORES its generation to its own slot; wave 0 polls all 256 slots
// with one dwordx4/lane until all >= gen. Deadlock-free: gens monotone, max
// skew one phase, ">= gen" absorbs it.
__device__ __forceinline__ void gbar(unsigned* arrive, unsigned gen) {
    asm volatile("s_waitcnt vmcnt(0)" ::: "memory");   // atomics/stores visible first
    __syncthreads();
    const int tid = threadIdx.x;
    if (tid == 0) st_dev_u32(arrive + blockIdx.x, gen);
    if (tid < 64) {
        for (;;) {
            vu4 a = ld_dev_u32x4(arrive + 4 * tid);    // 64 lanes x 4 = all 256 slots
            bool ok = a.x >= gen && a.y >= gen && a.z >= gen && a.w >= gen;
            if (__all(ok)) break;
            __builtin_amdgcn_s_sleep(2);
        }
    }
    __syncthreads();
    asm volatile("" ::: "memory");
}

// Zero all per-iteration colacc slots + arrive flags (stream-ordered before
// k_sink, so no in-kernel setup barrier is needed).
__global__ void k_binit(float4* colz, unsigned* arrive) {
    int i = blockIdx.x * blockDim.x + threadIdx.x;
    if (i < NITER * NN / 2) colz[i] = make_float4(0.f, 0.f, 0.f, 0.f);
    if (i < NBLK) arrive[i] = 0u;
}

// Persistent kernel: E (fp16) in LDS for all 20 iterations.
// ONE barrier per iteration (round-6 measured ~12 us/iter in barriers at 2/iter;
// phase D eliminated):
//   C: block's 16-row partial col sums -> HW atomicAdd into colacc[t] (LLC,
//      cross-XCD coherent: proven by round-0 baseline on this harness)
//   gbar   (colacc[t] complete)
//   R: v = 1/colacc[t] staged in LDS; per-wave row sums -> u (block-local)
// Numerics: t<19 entirely fp32 (trajectory error ~1e-6 << fp16-E floor 5e-4);
// t=19 C recomputes E from W in fp64 and R accumulates fp64 -> the lv/lu that
// feed P and the argmax are bit-identical to the previous passing version.
__global__ __launch_bounds__(TPB, 4) void k_sink(
    const float* __restrict__ W, float* __restrict__ P, float* __restrict__ H,
    double* __restrict__ colacc, // [NITER][NN] fp64 slots; fp32-aliased for t<19
    unsigned* __restrict__ arrive)
{
    extern __shared__ char smem[];
    __half* Eh     = (__half*)(smem + EH_OFF);
    float*  vbuf   = (float*) (smem + VB_OFF);
    double* u_lds  = (double*)(smem + U_OFF);
    float*  uf_lds = (float*) (smem + UF_OFF);

    const int tid = threadIdx.x;
    const int l   = tid & 63;
    const int w   = tid >> 6;        // wave id == local row id
    const int b   = blockIdx.x;
    unsigned gen  = 0;

    // ---- setup: Eh[w][:] = fp16(exp(W[row])), u = 1 ----
    {
        const float4* wp = (const float4*)(W + (size_t)(b * ROWS + w) * NN) + l;
        #pragma unroll
        for (int k = 0; k < 16; ++k) {
            float4 x = wp[k * 64];
            U8 p;
            p.h[0] = __floats2half2_rn(expf(x.x), expf(x.y));
            p.h[1] = __floats2half2_rn(expf(x.z), expf(x.w));
            *(ushort4*)(Eh + w * NN + 4 * (l + 64 * k)) = p.s;   // 8 B/lane, contiguous
        }
        if (tid < ROWS) { u_lds[tid] = 1.0; uf_lds[tid] = 1.0f; }
    }
    __syncthreads();

    for (int t = 0; t < NITER; ++t) {
        double* colD = colacc + (size_t)t * NN;
        float*  colF = (float*)colD;
        const int c0 = tid * 4;               // thread owns cols c0..c0+3

        // ---------- phase C: partial col sums over this block's 16 rows ----------
        if (t < NITER - 1) {
            float b0 = 0.f, b1 = 0.f, b2 = 0.f, b3 = 0.f;
            #pragma unroll
            for (int i = 0; i < ROWS; ++i) {
                U8 e; e.s = *(const ushort4*)(Eh + i * NN + c0);  // 8 B/lane, conflict-free
                float uu = uf_lds[i];                              // LDS broadcast
                float2 f01 = __half22float2(e.h[0]);
                float2 f23 = __half22float2(e.h[1]);
                b0 = fmaf(f01.x, uu, b0);
                b1 = fmaf(f01.y, uu, b1);
                b2 = fmaf(f23.x, uu, b2);
                b3 = fmaf(f23.y, uu, b3);
            }
            unsafeAtomicAdd(colF + c0 + 0, b0);   // global_atomic_add_f32 @ LLC
            unsafeAtomicAdd(colF + c0 + 1, b1);
            unsafeAtomicAdd(colF + c0 + 2, b2);
            unsafeAtomicAdd(colF + c0 + 3, b3);
        } else {
            // high-precision last col pass: recompute E from W (LLC-resident) in fp64
            double a0 = 0, a1 = 0, a2 = 0, a3 = 0;
            #pragma unroll 4
            for (int i = 0; i < ROWS; ++i) {
                float4 x = *(const float4*)(W + (size_t)(b * ROWS + i) * NN + c0);
                double uu = u_lds[i];
                a0 = fma(exp_hi((double)x.x), uu, a0);
                a1 = fma(exp_hi((double)x.y), uu, a1);
                a2 = fma(exp_hi((double)x.z), uu, a2);
                a3 = fma(exp_hi((double)x.w), uu, a3);
            }
            unsafeAtomicAdd(colD + c0 + 0, a0);   // global_atomic_add_f64 @ LLC
            unsafeAtomicAdd(colD + c0 + 1, a1);
            unsafeAtomicAdd(colD + c0 + 2, a2);
            unsafeAtomicAdd(colD + c0 + 3, a3);
        }
        gbar(arrive, ++gen);                       // colacc[t] complete grid-wide

        // ---------- phase R: u_i = 1 / sum_j E_ij * v_j (u stays block-local) ----------
        if (t < NITER - 1) {
            const int j0 = tid * 4;
            vf4 cf = ld_dev_f4(colF + j0);         // 16 B/thread, contiguous, LLC
            vbuf[j0 + 0] = 1.0f / cf.x;
            vbuf[j0 + 1] = 1.0f / cf.y;
            vbuf[j0 + 2] = 1.0f / cf.z;
            vbuf[j0 + 3] = 1.0f / cf.w;
            __syncthreads();
            float a4 = 0.f, a5 = 0.f, a6 = 0.f, a7 = 0.f;
            #pragma unroll
            for (int k = 0; k < 16; ++k) {
                const int cc = 256 * k + 4 * l;
                U8 e; e.s = *(const ushort4*)(Eh + w * NN + cc);  // conflict-free
                float4 vv = *(const float4*)(vbuf + cc);          // conflict-free
                float2 f01 = __half22float2(e.h[0]);
                float2 f23 = __half22float2(e.h[1]);
                a4 = fmaf(f01.x, vv.x, a4);
                a5 = fmaf(f01.y, vv.y, a5);
                a6 = fmaf(f23.x, vv.z, a6);
                a7 = fmaf(f23.y, vv.w, a7);
            }
            float acc = (a4 + a5) + (a6 + a7);
            #pragma unroll
            for (int off = 32; off > 0; off >>= 1)
                acc += __shfl_xor(acc, off, 64);
            if (l == 0) { float r = 1.0f / acc; u_lds[w] = (double)r; uf_lds[w] = r; }
        } else {
            // t=19: fp64-accum path (identical numerics to previous passing version)
            const int j0 = tid * 4;
            DF x, y;
            ld2_dev_d2(colD + j0, colD + j0 + 2, x.f, y.f);
            vbuf[j0 + 0] = (float)(1.0 / x.d[0]);
            vbuf[j0 + 1] = (float)(1.0 / x.d[1]);
            vbuf[j0 + 2] = (float)(1.0 / y.d[0]);
            vbuf[j0 + 3] = (float)(1.0 / y.d[1]);
            __syncthreads();
            double a4 = 0, a5 = 0, a6 = 0, a7 = 0;
            #pragma unroll
            for (int k = 0; k < 16; ++k) {
                const int cc = 256 * k + 4 * l;
                U8 e; e.s = *(const ushort4*)(Eh + w * NN + cc);
                float4 vv = *(const float4*)(vbuf + cc);
                float2 f01 = __half22float2(e.h[0]);
                float2 f23 = __half22float2(e.h[1]);
                a4 = fma((double)f01.x, (double)vv.x, a4);
                a5 = fma((double)f01.y, (double)vv.y, a5);
                a6 = fma((double)f23.x, (double)vv.z, a6);
                a7 = fma((double)f23.y, (double)vv.w, a7);
            }
            double acc = (a4 + a5) + (a6 + a7);
            #pragma unroll
            for (int off = 32; off > 0; off >>= 1)
                acc += __shfl_xor(acc, off, 64);
            if (l == 0) u_lds[w] = 1.0 / acc;
        }
        __syncthreads();   // publish u for next C (block-local only)
    }

    // ---------- final: P = exp(W + lv + lu); H = one-hot(argmax(W + lv)) ----------
    const double* colD19 = colacc + (size_t)(NITER - 1) * NN;
    double* lv = (double*)smem;                        // alias Eh (E no longer needed)
    {
        const int j0 = tid * 4;
        DF x, y;
        ld2_dev_d2(colD19 + j0, colD19 + j0 + 2, x.f, y.f);
        lv[j0 + 0] = -log(x.d[0]);
        lv[j0 + 1] = -log(x.d[1]);
        lv[j0 + 2] = -log(y.d[0]);
        lv[j0 + 3] = -log(y.d[1]);
    }
    __syncthreads();
    {
        const size_t i = (size_t)(b * ROWS + w);
        const float2* wp = (const float2*)(W + i * NN) + l;
        float2* pp = (float2*)(P + i * NN) + l;
        float2* hp = (float2*)(H + i * NN) + l;
        const double lu = log(u_lds[w]);

        double besty = -1e300;
        int bestj = 0;
        #pragma unroll 4
        for (int k = 0; k < 32; ++k) {
            float2 x = wp[k * 64];                     // 8 B/lane, 512 B/wave coalesced
            int jb = k * 128 + l * 2;
            double2 lvv = *(const double2*)(lv + jb);  // 16 B/lane, conflict-free
            double y0 = (double)x.x + lvv.x;
            double y1 = (double)x.y + lvv.y;
            float2 pv;
            pv.x = expf((float)(y0 + lu));
            pv.y = expf((float)(y1 + lu));
            pp[k * 64] = pv;
            if (y0 > besty) { besty = y0; bestj = jb + 0; }   // strict > keeps first index
            if (y1 > besty) { besty = y1; bestj = jb + 1; }
        }
        for (int off = 32; off > 0; off >>= 1) {
            double oy = __shfl_xor(besty, off, 64);
            int    oj = __shfl_xor(bestj, off, 64);
            if (oy > besty || (oy == besty && oj < bestj)) { besty = oy; bestj = oj; }
        }
        #pragma unroll 4
        for (int k = 0; k < 32; ++k) {
            int jb = k * 128 + l * 2;
            float2 hv;
            hv.x = (jb + 0 == bestj) ? 1.0f : 0.0f;
            hv.y = (jb + 1 == bestj) ? 1.0f : 0.0f;
            hp[k * 64] = hv;
        }
    }
}

extern "C" void kernel_launch(void* const* d_in, const int* in_sizes, int n_in,
                              void* d_out, int out_size, void* d_ws, size_t ws_size,
                              hipStream_t stream) {
    const float* W = (const float*)d_in[0];
    float* P = (float*)d_out;                     // P_hat
    float* H = P + (size_t)NN * NN;               // P_hat_hard (one-hot numerically)

    double*   colacc = (double*)d_ws;                      // [NITER][NN] = 640 KB
    unsigned* arrive = (unsigned*)(colacc + (size_t)NITER * NN);

    static bool attr_done = false;
    if (!attr_done) {
        (void)hipFuncSetAttribute((const void*)k_sink,
                                  hipFuncAttributeMaxDynamicSharedMemorySize,
                                  SMEM_BYTES);
        attr_done = true;
    }

    k_binit<<<(NITER * NN / 2 + 255) / 256, 256, 0, stream>>>((float4*)colacc, arrive);

    void* args[] = {(void*)&W, (void*)&P, (void*)&H, (void*)&colacc, (void*)&arrive};
    (void)hipLaunchCooperativeKernel((const void*)k_sink, dim3(NBLK), dim3(TPB),
                                     args, SMEM_BYTES, stream);
}

// Round 8
// 391.522 us; speedup vs baseline: 3.1532x; 3.1532x over previous
//
#include <hip/hip_runtime.h>
#include <hip/hip_fp16.h>
#include <math.h>

#define NN    4096
#define NITER 20
#define TPB   1024
#define NBLK  256     // == CU count; 1 block/CU (forced by LDS)
#define ROWS  16      // rows of E per block

// ---- dynamic LDS layout ----
#define EH_OFF    0        // __half Eh[16][4096]           = 131072 B
#define VB_OFF    131072   // float  vbuf[4096]             =  16384 B
#define WF_OFF    147456   // float  wredF[16][16]          =   1024 B
#define WD_OFF    148480   // double wredD[16][16]          =   2048 B
#define U_OFF     150528   // double u_lds[16]              =    128 B
#define UF_OFF    150656   // float  uf_lds[16]             =     64 B
#define SMEM_BYTES 150720
// final phase aliases lv[4096] (double, 32 KB) onto Eh space.

// Native ext-vector types: required for inline-asm "v" constraints.
typedef float    vf4 __attribute__((ext_vector_type(4)));

// exp of a double argument with fp32 exp + first-order fp64 correction.
__device__ __forceinline__ double exp_hi(double x) {
    float xf = (float)x;
    double dl = x - (double)xf;
    double e = (double)expf(xf);
    return fma(e, dl, e);
}

union U8 { ushort4 s; __half2 h[2]; };   // 8 B = 4 halves
union DF { double d[2]; vf4 f; };        // fp64 pair <-> 16B asm payload

// ---- device-scope PLAIN memory ops (sc1: bypass L1+per-XCD L2, serve at LLC).
__device__ __forceinline__ void st_dev_f4(float* p, vf4 v) {
    asm volatile("global_store_dwordx4 %0, %1, off sc1" :: "v"(p), "v"(v) : "memory");
}
__device__ __forceinline__ void st_dev_f1(float* p, float v) {
    asm volatile("global_store_dword %0, %1, off sc1" :: "v"(p), "v"(v) : "memory");
}
__device__ __forceinline__ void st_dev_d2(double* p, double a, double b) {
    DF u; u.d[0] = a; u.d[1] = b;
    asm volatile("global_store_dwordx4 %0, %1, off sc1" :: "v"(p), "v"(u.f) : "memory");
}
__device__ __forceinline__ void st_dev_d1(double* p, double v) {
    asm volatile("global_store_dwordx2 %0, %1, off sc1" :: "v"(p), "v"(v) : "memory");
}
__device__ __forceinline__ vf4 ld_dev_f4(const float* p) {
    vf4 r;
    asm volatile("global_load_dwordx4 %0, %1, off sc1\n\ts_waitcnt vmcnt(0)"
                 : "=v"(r) : "v"(p) : "memory");
    return r;
}
__device__ __forceinline__ void ld4_dev_f(const float* p0, const float* p1,
                                          const float* p2, const float* p3,
                                          float& a0, float& a1, float& a2, float& a3) {
    asm volatile(
        "global_load_dword %0, %4, off sc1\n\t"
        "global_load_dword %1, %5, off sc1\n\t"
        "global_load_dword %2, %6, off sc1\n\t"
        "global_load_dword %3, %7, off sc1\n\t"
        "s_waitcnt vmcnt(0)"
        : "=&v"(a0), "=&v"(a1), "=&v"(a2), "=&v"(a3)
        : "v"(p0), "v"(p1), "v"(p2), "v"(p3) : "memory");
}
__device__ __forceinline__ void ld4_dev_d(const double* p0, const double* p1,
                                          const double* p2, const double* p3,
                                          double& a0, double& a1, double& a2, double& a3) {
    asm volatile(
        "global_load_dwordx2 %0, %4, off sc1\n\t"
        "global_load_dwordx2 %1, %5, off sc1\n\t"
        "global_load_dwordx2 %2, %6, off sc1\n\t"
        "global_load_dwordx2 %3, %7, off sc1\n\t"
        "s_waitcnt vmcnt(0)"
        : "=&v"(a0), "=&v"(a1), "=&v"(a2), "=&v"(a3)
        : "v"(p0), "v"(p1), "v"(p2), "v"(p3) : "memory");
}
__device__ __forceinline__ void ld2_dev_d2(const double* p0, const double* p1,
                                           vf4& x, vf4& y) {
    asm volatile(
        "global_load_dwordx4 %0, %2, off sc1\n\t"
        "global_load_dwordx4 %1, %3, off sc1\n\t"
        "s_waitcnt vmcnt(0)"
        : "=&v"(x), "=&v"(y)
        : "v"(p0), "v"(p1) : "memory");
}

// Zero bufF + partD + colF + colD (normal stores; k_binit's end-of-kernel
// implicit agent release flushes L2, so k_sink's sc1 LLC reads see them).
#define ZTOT ((2 * NBLK * NN * 4 + NBLK * NN * 8 + NITER * NN * 4 + NN * 8) / 16)
__global__ void k_binit(float4* z) {
    int i = blockIdx.x * blockDim.x + threadIdx.x;
    if (i < ZTOT) z[i] = make_float4(0.f, 0.f, 0.f, 0.f);
}

// Persistent kernel, ZERO grid barriers — all cross-block sync is data-flow:
// every exchanged value is strictly positive (sums of exp(W)*u, u>0), so
// "present" is encoded in the data. Per iteration:
//   C: block's 16-row partial col sums -> bufF[t&1] (fp32, sc1), stored
//      multiplied by sign s(t)=((t>>1)&1)?-1:+1 so stale (t-2) data in the
//      double buffer always has the WRONG sign; unwritten = 0 = rejected.
//   D: spin-reload the 256 needed partials until all have sign s(t);
//      reduce -> colF[t] (per-iteration slot, zero-init, written once).
//   R: spin until this thread's colF[t] values != 0 (this IS the second
//      barrier, fused with the data read); v in LDS; row sums -> u.
// Reuse safety: C(t+2) overwrites bufF[t&1] only after R(t+1), which needs
// all of colF[t+1], which needs every block's D(t+1), which follows that
// block's D(t) reads in program order. Proven no write-under-read.
// Numerics: t<19 fp32 (round-7 hardware-validated: identical absmax); t=19
// recomputes E from W in fp64 (partD/colD) -> lv/lu/argmax bit-identical.
__global__ __launch_bounds__(TPB, 4) void k_sink(
    const float* __restrict__ W, float* __restrict__ P, float* __restrict__ H,
    float*  __restrict__ bufF,   // [2][NBLK][NN] fp32 partials (sign-tagged)
    double* __restrict__ partD,  // [NBLK][NN] fp64 partials for t=19
    float*  __restrict__ colF,   // [NITER][NN] fp32 colsums (t<19)
    double* __restrict__ colD)   // [NN] fp64 colsums (t=19)
{
    extern __shared__ char smem[];
    __half* Eh     = (__half*)(smem + EH_OFF);
    float*  vbuf   = (float*) (smem + VB_OFF);
    float*  wredF  = (float*) (smem + WF_OFF);
    double* wredD  = (double*)(smem + WD_OFF);
    double* u_lds  = (double*)(smem + U_OFF);
    float*  uf_lds = (float*) (smem + UF_OFF);

    const int tid = threadIdx.x;
    const int l   = tid & 63;
    const int w   = tid >> 6;        // wave id == local row id
    const int b   = blockIdx.x;

    // ---- setup: Eh[w][:] = fp16(exp(W[row])), u = 1 ----
    {
        const float4* wp = (const float4*)(W + (size_t)(b * ROWS + w) * NN) + l;
        #pragma unroll
        for (int k = 0; k < 16; ++k) {
            float4 x = wp[k * 64];
            U8 p;
            p.h[0] = __floats2half2_rn(expf(x.x), expf(x.y));
            p.h[1] = __floats2half2_rn(expf(x.z), expf(x.w));
            *(ushort4*)(Eh + w * NN + 4 * (l + 64 * k)) = p.s;   // 8 B/lane, contiguous
        }
        if (tid < ROWS) { u_lds[tid] = 1.0; uf_lds[tid] = 1.0f; }
    }
    __syncthreads();

    for (int t = 0; t < NITER; ++t) {
        const int   c0 = tid * 4;                       // thread owns cols c0..c0+3
        const float sg = ((t >> 1) & 1) ? -1.f : 1.f;   // freshness sign for bufF[t&1]
        float* bF = bufF + (size_t)(t & 1) * NBLK * NN;
        float* cF = colF + (size_t)t * NN;

        // ---------- phase C: partial col sums over this block's 16 rows ----------
        if (t < NITER - 1) {
            float b0 = 0.f, b1 = 0.f, b2 = 0.f, b3 = 0.f;
            #pragma unroll
            for (int i = 0; i < ROWS; ++i) {
                U8 e; e.s = *(const ushort4*)(Eh + i * NN + c0);  // conflict-free
                float uu = uf_lds[i];                              // LDS broadcast
                float2 f01 = __half22float2(e.h[0]);
                float2 f23 = __half22float2(e.h[1]);
                b0 = fmaf(f01.x, uu, b0);
                b1 = fmaf(f01.y, uu, b1);
                b2 = fmaf(f23.x, uu, b2);
                b3 = fmaf(f23.y, uu, b3);
            }
            vf4 pv = {b0 * sg, b1 * sg, b2 * sg, b3 * sg};
            st_dev_f4(bF + (size_t)b * NN + c0, pv);    // fire-and-forget to LLC
        } else {
            // high-precision last col pass: recompute E from W in fp64
            double a0 = 0, a1 = 0, a2 = 0, a3 = 0;
            #pragma unroll 4
            for (int i = 0; i < ROWS; ++i) {
                float4 x = *(const float4*)(W + (size_t)(b * ROWS + i) * NN + c0);
                double uu = u_lds[i];
                a0 = fma(exp_hi((double)x.x), uu, a0);
                a1 = fma(exp_hi((double)x.y), uu, a1);
                a2 = fma(exp_hi((double)x.z), uu, a2);
                a3 = fma(exp_hi((double)x.w), uu, a3);
            }
            st_dev_d2(partD + (size_t)b * NN + c0,     a0, a1);
            st_dev_d2(partD + (size_t)b * NN + c0 + 2, a2, a3);
        }

        // ---------- phase D: reduce 256 partials for block's 16 columns ----------
        {
            const int c  = (b << 4) + (tid & 15);
            const int r0 = tid >> 4;                    // 0..63
            if (t < NITER - 1) {
                float f0, f1, f2, f3;
                for (;;) {                              // spin: sign s(t) == fresh
                    ld4_dev_f(&bF[(size_t)(r0 +   0) * NN + c],
                              &bF[(size_t)(r0 +  64) * NN + c],
                              &bF[(size_t)(r0 + 128) * NN + c],
                              &bF[(size_t)(r0 + 192) * NN + c], f0, f1, f2, f3);
                    bool ok = (f0 * sg > 0.f) && (f1 * sg > 0.f) &&
                              (f2 * sg > 0.f) && (f3 * sg > 0.f);
                    if (__all(ok)) break;
                    __builtin_amdgcn_s_sleep(2);
                }
                float s = (((f0 + f1) + (f2 + f3))) * sg;
                s += __shfl_xor(s, 16, 64);
                s += __shfl_xor(s, 32, 64);
                if (l < 16) wredF[w * 16 + l] = s;
                __syncthreads();
                if (tid < 64) {
                    const int c2 = l & 15, g = l >> 4;
                    float s2 = wredF[g * 16 + c2] + wredF[(g + 4) * 16 + c2]
                             + wredF[(g + 8) * 16 + c2] + wredF[(g + 12) * 16 + c2];
                    s2 += __shfl_xor(s2, 16, 64);
                    s2 += __shfl_xor(s2, 32, 64);
                    if (l < 16) st_dev_f1(&cF[(b << 4) + l], s2);
                }
            } else {
                double d0, d1, d2, d3;
                for (;;) {                              // spin: nonzero == written
                    ld4_dev_d(&partD[(size_t)(r0 +   0) * NN + c],
                              &partD[(size_t)(r0 +  64) * NN + c],
                              &partD[(size_t)(r0 + 128) * NN + c],
                              &partD[(size_t)(r0 + 192) * NN + c], d0, d1, d2, d3);
                    bool ok = (d0 > 0.0) && (d1 > 0.0) && (d2 > 0.0) && (d3 > 0.0);
                    if (__all(ok)) break;
                    __builtin_amdgcn_s_sleep(2);
                }
                double s = (d0 + d1) + (d2 + d3);
                s += __shfl_xor(s, 16, 64);
                s += __shfl_xor(s, 32, 64);
                if (l < 16) wredD[w * 16 + l] = s;
                __syncthreads();
                if (tid < 64) {
                    const int c2 = l & 15, g = l >> 4;
                    double s2 = wredD[g * 16 + c2] + wredD[(g + 4) * 16 + c2]
                              + wredD[(g + 8) * 16 + c2] + wredD[(g + 12) * 16 + c2];
                    s2 += __shfl_xor(s2, 16, 64);
                    s2 += __shfl_xor(s2, 32, 64);
                    if (l < 16) st_dev_d1(&colD[(b << 4) + l], s2);
                }
            }
        }

        // ---------- phase R: u_i = 1 / sum_j E_ij * v_j (u stays block-local) ----------
        if (t < NITER - 1) {
            const int j0 = tid * 4;
            vf4 cf;
            for (;;) {                                  // data-flow barrier: colF[t]
                cf = ld_dev_f4(cF + j0);
                if (__all(cf.x > 0.f && cf.y > 0.f && cf.z > 0.f && cf.w > 0.f)) break;
                __builtin_amdgcn_s_sleep(2);
            }
            vbuf[j0 + 0] = 1.0f / cf.x;
            vbuf[j0 + 1] = 1.0f / cf.y;
            vbuf[j0 + 2] = 1.0f / cf.z;
            vbuf[j0 + 3] = 1.0f / cf.w;
            __syncthreads();
            float a4 = 0.f, a5 = 0.f, a6 = 0.f, a7 = 0.f;
            #pragma unroll
            for (int k = 0; k < 16; ++k) {
                const int cc = 256 * k + 4 * l;
                U8 e; e.s = *(const ushort4*)(Eh + w * NN + cc);  // conflict-free
                float4 vv = *(const float4*)(vbuf + cc);          // conflict-free
                float2 f01 = __half22float2(e.h[0]);
                float2 f23 = __half22float2(e.h[1]);
                a4 = fmaf(f01.x, vv.x, a4);
                a5 = fmaf(f01.y, vv.y, a5);
                a6 = fmaf(f23.x, vv.z, a6);
                a7 = fmaf(f23.y, vv.w, a7);
            }
            float acc = (a4 + a5) + (a6 + a7);
            #pragma unroll
            for (int off = 32; off > 0; off >>= 1)
                acc += __shfl_xor(acc, off, 64);
            if (l == 0) { float r = 1.0f / acc; u_lds[w] = (double)r; uf_lds[w] = r; }
        } else {
            // t=19: fp64 colsums -> v; fp64-accum row pass (argmax-grade numerics)
            const int j0 = tid * 4;
            DF x, y;
            for (;;) {
                ld2_dev_d2(colD + j0, colD + j0 + 2, x.f, y.f);
                if (__all(x.d[0] > 0.0 && x.d[1] > 0.0 &&
                          y.d[0] > 0.0 && y.d[1] > 0.0)) break;
                __builtin_amdgcn_s_sleep(2);
            }
            vbuf[j0 + 0] = (float)(1.0 / x.d[0]);
            vbuf[j0 + 1] = (float)(1.0 / x.d[1]);
            vbuf[j0 + 2] = (float)(1.0 / y.d[0]);
            vbuf[j0 + 3] = (float)(1.0 / y.d[1]);
            __syncthreads();
            double a4 = 0, a5 = 0, a6 = 0, a7 = 0;
            #pragma unroll
            for (int k = 0; k < 16; ++k) {
                const int cc = 256 * k + 4 * l;
                U8 e; e.s = *(const ushort4*)(Eh + w * NN + cc);
                float4 vv = *(const float4*)(vbuf + cc);
                float2 f01 = __half22float2(e.h[0]);
                float2 f23 = __half22float2(e.h[1]);
                a4 = fma((double)f01.x, (double)vv.x, a4);
                a5 = fma((double)f01.y, (double)vv.y, a5);
                a6 = fma((double)f23.x, (double)vv.z, a6);
                a7 = fma((double)f23.y, (double)vv.w, a7);
            }
            double acc = (a4 + a5) + (a6 + a7);
            #pragma unroll
            for (int off = 32; off > 0; off >>= 1)
                acc += __shfl_xor(acc, off, 64);
            if (l == 0) u_lds[w] = 1.0 / acc;
        }
        __syncthreads();   // publish u for next C (block-local only)
    }

    // ---------- final: P = exp(W + lv + lu); H = one-hot(argmax(W + lv)) ----------
    double* lv = (double*)smem;                        // alias Eh (E no longer needed)
    {
        const int j0 = tid * 4;
        DF x, y;
        ld2_dev_d2(colD + j0, colD + j0 + 2, x.f, y.f);  // presence proven by R(19)
        lv[j0 + 0] = -log(x.d[0]);
        lv[j0 + 1] = -log(x.d[1]);
        lv[j0 + 2] = -log(y.d[0]);
        lv[j0 + 3] = -log(y.d[1]);
    }
    __syncthreads();
    {
        const size_t i = (size_t)(b * ROWS + w);
        const float2* wp = (const float2*)(W + i * NN) + l;
        float2* pp = (float2*)(P + i * NN) + l;
        float2* hp = (float2*)(H + i * NN) + l;
        const double lu = log(u_lds[w]);

        double besty = -1e300;
        int bestj = 0;
        #pragma unroll 4
        for (int k = 0; k < 32; ++k) {
            float2 x = wp[k * 64];                     // 8 B/lane, 512 B/wave coalesced
            int jb = k * 128 + l * 2;
            double2 lvv = *(const double2*)(lv + jb);  // 16 B/lane, conflict-free
            double y0 = (double)x.x + lvv.x;
            double y1 = (double)x.y + lvv.y;
            float2 pv;
            pv.x = expf((float)(y0 + lu));
            pv.y = expf((float)(y1 + lu));
            pp[k * 64] = pv;
            if (y0 > besty) { besty = y0; bestj = jb + 0; }   // strict > keeps first index
            if (y1 > besty) { besty = y1; bestj = jb + 1; }
        }
        for (int off = 32; off > 0; off >>= 1) {
            double oy = __shfl_xor(besty, off, 64);
            int    oj = __shfl_xor(bestj, off, 64);
            if (oy > besty || (oy == besty && oj < bestj)) { besty = oy; bestj = oj; }
        }
        #pragma unroll 4
        for (int k = 0; k < 32; ++k) {
            int jb = k * 128 + l * 2;
            float2 hv;
            hv.x = (jb + 0 == bestj) ? 1.0f : 0.0f;
            hv.y = (jb + 1 == bestj) ? 1.0f : 0.0f;
            hp[k * 64] = hv;
        }
    }
}

extern "C" void kernel_launch(void* const* d_in, const int* in_sizes, int n_in,
                              void* d_out, int out_size, void* d_ws, size_t ws_size,
                              hipStream_t stream) {
    const float* W = (const float*)d_in[0];
    float* P = (float*)d_out;                     // P_hat
    float* H = P + (size_t)NN * NN;               // P_hat_hard (one-hot numerically)

    float*  bufF  = (float*)d_ws;                          // 8 MiB
    double* partD = (double*)(bufF + 2 * (size_t)NBLK * NN);   // 8 MiB
    float*  colF  = (float*)(partD + (size_t)NBLK * NN);       // 320 KiB
    double* colD  = (double*)(colF + (size_t)NITER * NN);      // 32 KiB

    static bool attr_done = false;
    if (!attr_done) {
        (void)hipFuncSetAttribute((const void*)k_sink,
                                  hipFuncAttributeMaxDynamicSharedMemorySize,
                                  SMEM_BYTES);
        attr_done = true;
    }

    k_binit<<<(ZTOT + 255) / 256, 256, 0, stream>>>((float4*)d_ws);

    void* args[] = {(void*)&W, (void*)&P, (void*)&H,
                    (void*)&bufF, (void*)&partD, (void*)&colF, (void*)&colD};
    (void)hipLaunchCooperativeKernel((const void*)k_sink, dim3(NBLK), dim3(TPB),
                                     args, SMEM_BYTES, stream);
}

// Round 9
// 373.435 us; speedup vs baseline: 3.3059x; 1.0484x over previous
//
#include <hip/hip_runtime.h>
#include <hip/hip_fp16.h>
#include <math.h>

#define NN    4096
#define NITER 20
#define TPB   1024
#define NBLK  256     // == CU count; 1 block/CU (forced by LDS)
#define ROWS  16      // rows of E per block

// ---- dynamic LDS layout ----
#define EH_OFF    0        // __half Eh[16][4096]           = 131072 B
#define VB_OFF    131072   // float  vbuf[4096]             =  16384 B
#define WF_OFF    147456   // float  wredF[16][16]          =   1024 B
#define WD_OFF    148480   // double wredD[16][16]          =   2048 B
#define U_OFF     150528   // double u_lds[16]              =    128 B
#define UF_OFF    150656   // float  uf_lds[16]             =     64 B
#define SMEM_BYTES 150720
// final phase aliases lv[4096] (double, 32 KB) onto Eh space.

// Native ext-vector types: required for inline-asm "v" constraints.
typedef float    vf4 __attribute__((ext_vector_type(4)));

// exp of a double argument with fp32 exp + first-order fp64 correction.
__device__ __forceinline__ double exp_hi(double x) {
    float xf = (float)x;
    double dl = x - (double)xf;
    double e = (double)expf(xf);
    return fma(e, dl, e);
}

union U8 { ushort4 s; __half2 h[2]; };   // 8 B = 4 halves
union DF { double d[2]; vf4 f; };        // fp64 pair <-> 16B asm payload

// ---- device-scope PLAIN memory ops (sc1: bypass L1+per-XCD L2, serve at LLC).
__device__ __forceinline__ void st_dev_f4(float* p, vf4 v) {
    asm volatile("global_store_dwordx4 %0, %1, off sc1" :: "v"(p), "v"(v) : "memory");
}
__device__ __forceinline__ void st_dev_f1(float* p, float v) {
    asm volatile("global_store_dword %0, %1, off sc1" :: "v"(p), "v"(v) : "memory");
}
__device__ __forceinline__ void st_dev_d2(double* p, double a, double b) {
    DF u; u.d[0] = a; u.d[1] = b;
    asm volatile("global_store_dwordx4 %0, %1, off sc1" :: "v"(p), "v"(u.f) : "memory");
}
__device__ __forceinline__ void st_dev_d1(double* p, double v) {
    asm volatile("global_store_dwordx2 %0, %1, off sc1" :: "v"(p), "v"(v) : "memory");
}
__device__ __forceinline__ vf4 ld_dev_f4(const float* p) {
    vf4 r;
    asm volatile("global_load_dwordx4 %0, %1, off sc1\n\ts_waitcnt vmcnt(0)"
                 : "=v"(r) : "v"(p) : "memory");
    return r;
}
__device__ __forceinline__ void ld4_dev_f(const float* p0, const float* p1,
                                          const float* p2, const float* p3,
                                          float& a0, float& a1, float& a2, float& a3) {
    asm volatile(
        "global_load_dword %0, %4, off sc1\n\t"
        "global_load_dword %1, %5, off sc1\n\t"
        "global_load_dword %2, %6, off sc1\n\t"
        "global_load_dword %3, %7, off sc1\n\t"
        "s_waitcnt vmcnt(0)"
        : "=&v"(a0), "=&v"(a1), "=&v"(a2), "=&v"(a3)
        : "v"(p0), "v"(p1), "v"(p2), "v"(p3) : "memory");
}
__device__ __forceinline__ void ld4_dev_d(const double* p0, const double* p1,
                                          const double* p2, const double* p3,
                                          double& a0, double& a1, double& a2, double& a3) {
    asm volatile(
        "global_load_dwordx2 %0, %4, off sc1\n\t"
        "global_load_dwordx2 %1, %5, off sc1\n\t"
        "global_load_dwordx2 %2, %6, off sc1\n\t"
        "global_load_dwordx2 %3, %7, off sc1\n\t"
        "s_waitcnt vmcnt(0)"
        : "=&v"(a0), "=&v"(a1), "=&v"(a2), "=&v"(a3)
        : "v"(p0), "v"(p1), "v"(p2), "v"(p3) : "memory");
}
__device__ __forceinline__ void ld2_dev_d2(const double* p0, const double* p1,
                                           vf4& x, vf4& y) {
    asm volatile(
        "global_load_dwordx4 %0, %2, off sc1\n\t"
        "global_load_dwordx4 %1, %3, off sc1\n\t"
        "s_waitcnt vmcnt(0)"
        : "=&v"(x), "=&v"(y)
        : "v"(p0), "v"(p1) : "memory");
}

// Zero bufF + partD + colF + colD (normal stores; k_binit's end-of-kernel
// implicit agent release flushes L2, so k_sink's sc1 LLC reads see them).
#define ZTOT ((2 * NBLK * NN * 4 + NBLK * NN * 8 + NITER * NN * 4 + NN * 8) / 16)
__global__ void k_binit(float4* z) {
    int i = blockIdx.x * blockDim.x + threadIdx.x;
    if (i < ZTOT) z[i] = make_float4(0.f, 0.f, 0.f, 0.f);
}

// Persistent kernel, ZERO grid barriers — all cross-block sync is data-flow:
// every exchanged value is strictly positive (sums of exp(W)*u, u>0), so
// "present" is encoded in the data. Per iteration:
//   C: block's 16-row partial col sums -> bufF[t&1] (fp32, sc1), stored
//      multiplied by sign s(t)=((t>>1)&1)?-1:+1 so stale (t-2) data in the
//      double buffer always has the WRONG sign; unwritten = 0 = rejected.
//   D: spin-reload the 256 needed partials until all have sign s(t);
//      reduce -> colF[t] (per-iteration slot, zero-init, written once).
//   R: spin until this thread's colF[t] values != 0 (this IS the second
//      barrier, fused with the data read); v in LDS; row sums -> u.
// Reuse safety: C(t+2) overwrites bufF[t&1] only after R(t+1), which needs
// all of colF[t+1], which needs every block's D(t+1), which follows that
// block's D(t) reads in program order. Proven no write-under-read.
// Numerics: t<19 fp32; t=19 recomputes E from W in fp64 (partD/colD) ->
// lv/lu/argmax bit-identical to the previous passing versions.
//
// PLAIN (non-cooperative) launch: no grid.sync anywhere, and co-residency is
// structural — 147 KB LDS forces 1 block/CU, grid == 256 == CU count, and
// nothing else runs concurrently (stream-ordered after k_binit), so all
// blocks are resident at dispatch; the data-flow spins cannot deadlock.
__global__ __launch_bounds__(TPB, 4) void k_sink(
    const float* __restrict__ W, float* __restrict__ P, float* __restrict__ H,
    float*  __restrict__ bufF,   // [2][NBLK][NN] fp32 partials (sign-tagged)
    double* __restrict__ partD,  // [NBLK][NN] fp64 partials for t=19
    float*  __restrict__ colF,   // [NITER][NN] fp32 colsums (t<19)
    double* __restrict__ colD)   // [NN] fp64 colsums (t=19)
{
    extern __shared__ char smem[];
    __half* Eh     = (__half*)(smem + EH_OFF);
    float*  vbuf   = (float*) (smem + VB_OFF);
    float*  wredF  = (float*) (smem + WF_OFF);
    double* wredD  = (double*)(smem + WD_OFF);
    double* u_lds  = (double*)(smem + U_OFF);
    float*  uf_lds = (float*) (smem + UF_OFF);

    const int tid = threadIdx.x;
    const int l   = tid & 63;
    const int w   = tid >> 6;        // wave id == local row id
    const int b   = blockIdx.x;

    // ---- setup: Eh[w][:] = fp16(exp(W[row])), u = 1 ----
    {
        const float4* wp = (const float4*)(W + (size_t)(b * ROWS + w) * NN) + l;
        #pragma unroll
        for (int k = 0; k < 16; ++k) {
            float4 x = wp[k * 64];
            U8 p;
            p.h[0] = __floats2half2_rn(expf(x.x), expf(x.y));
            p.h[1] = __floats2half2_rn(expf(x.z), expf(x.w));
            *(ushort4*)(Eh + w * NN + 4 * (l + 64 * k)) = p.s;   // 8 B/lane, contiguous
        }
        if (tid < ROWS) { u_lds[tid] = 1.0; uf_lds[tid] = 1.0f; }
    }
    __syncthreads();

    for (int t = 0; t < NITER; ++t) {
        const int   c0 = tid * 4;                       // thread owns cols c0..c0+3
        const float sg = ((t >> 1) & 1) ? -1.f : 1.f;   // freshness sign for bufF[t&1]
        float* bF = bufF + (size_t)(t & 1) * NBLK * NN;
        float* cF = colF + (size_t)t * NN;

        // ---------- phase C: partial col sums over this block's 16 rows ----------
        if (t < NITER - 1) {
            float b0 = 0.f, b1 = 0.f, b2 = 0.f, b3 = 0.f;
            #pragma unroll
            for (int i = 0; i < ROWS; ++i) {
                U8 e; e.s = *(const ushort4*)(Eh + i * NN + c0);  // conflict-free
                float uu = uf_lds[i];                              // LDS broadcast
                float2 f01 = __half22float2(e.h[0]);
                float2 f23 = __half22float2(e.h[1]);
                b0 = fmaf(f01.x, uu, b0);
                b1 = fmaf(f01.y, uu, b1);
                b2 = fmaf(f23.x, uu, b2);
                b3 = fmaf(f23.y, uu, b3);
            }
            vf4 pv = {b0 * sg, b1 * sg, b2 * sg, b3 * sg};
            st_dev_f4(bF + (size_t)b * NN + c0, pv);    // fire-and-forget to LLC
        } else {
            // high-precision last col pass: recompute E from W in fp64
            double a0 = 0, a1 = 0, a2 = 0, a3 = 0;
            #pragma unroll 4
            for (int i = 0; i < ROWS; ++i) {
                float4 x = *(const float4*)(W + (size_t)(b * ROWS + i) * NN + c0);
                double uu = u_lds[i];
                a0 = fma(exp_hi((double)x.x), uu, a0);
                a1 = fma(exp_hi((double)x.y), uu, a1);
                a2 = fma(exp_hi((double)x.z), uu, a2);
                a3 = fma(exp_hi((double)x.w), uu, a3);
            }
            st_dev_d2(partD + (size_t)b * NN + c0,     a0, a1);
            st_dev_d2(partD + (size_t)b * NN + c0 + 2, a2, a3);
        }

        // ---------- phase D: reduce 256 partials for block's 16 columns ----------
        {
            const int c  = (b << 4) + (tid & 15);
            const int r0 = tid >> 4;                    // 0..63
            if (t < NITER - 1) {
                float f0, f1, f2, f3;
                for (;;) {                              // spin: sign s(t) == fresh
                    ld4_dev_f(&bF[(size_t)(r0 +   0) * NN + c],
                              &bF[(size_t)(r0 +  64) * NN + c],
                              &bF[(size_t)(r0 + 128) * NN + c],
                              &bF[(size_t)(r0 + 192) * NN + c], f0, f1, f2, f3);
                    bool ok = (f0 * sg > 0.f) && (f1 * sg > 0.f) &&
                              (f2 * sg > 0.f) && (f3 * sg > 0.f);
                    if (__all(ok)) break;
                    __builtin_amdgcn_s_sleep(2);
                }
                float s = (((f0 + f1) + (f2 + f3))) * sg;
                s += __shfl_xor(s, 16, 64);
                s += __shfl_xor(s, 32, 64);
                if (l < 16) wredF[w * 16 + l] = s;
                __syncthreads();
                if (tid < 64) {
                    const int c2 = l & 15, g = l >> 4;
                    float s2 = wredF[g * 16 + c2] + wredF[(g + 4) * 16 + c2]
                             + wredF[(g + 8) * 16 + c2] + wredF[(g + 12) * 16 + c2];
                    s2 += __shfl_xor(s2, 16, 64);
                    s2 += __shfl_xor(s2, 32, 64);
                    if (l < 16) st_dev_f1(&cF[(b << 4) + l], s2);
                }
            } else {
                double d0, d1, d2, d3;
                for (;;) {                              // spin: nonzero == written
                    ld4_dev_d(&partD[(size_t)(r0 +   0) * NN + c],
                              &partD[(size_t)(r0 +  64) * NN + c],
                              &partD[(size_t)(r0 + 128) * NN + c],
                              &partD[(size_t)(r0 + 192) * NN + c], d0, d1, d2, d3);
                    bool ok = (d0 > 0.0) && (d1 > 0.0) && (d2 > 0.0) && (d3 > 0.0);
                    if (__all(ok)) break;
                    __builtin_amdgcn_s_sleep(2);
                }
                double s = (d0 + d1) + (d2 + d3);
                s += __shfl_xor(s, 16, 64);
                s += __shfl_xor(s, 32, 64);
                if (l < 16) wredD[w * 16 + l] = s;
                __syncthreads();
                if (tid < 64) {
                    const int c2 = l & 15, g = l >> 4;
                    double s2 = wredD[g * 16 + c2] + wredD[(g + 4) * 16 + c2]
                              + wredD[(g + 8) * 16 + c2] + wredD[(g + 12) * 16 + c2];
                    s2 += __shfl_xor(s2, 16, 64);
                    s2 += __shfl_xor(s2, 32, 64);
                    if (l < 16) st_dev_d1(&colD[(b << 4) + l], s2);
                }
            }
        }

        // ---------- phase R: u_i = 1 / sum_j E_ij * v_j (u stays block-local) ----------
        if (t < NITER - 1) {
            const int j0 = tid * 4;
            vf4 cf;
            for (;;) {                                  // data-flow barrier: colF[t]
                cf = ld_dev_f4(cF + j0);
                if (__all(cf.x > 0.f && cf.y > 0.f && cf.z > 0.f && cf.w > 0.f)) break;
                __builtin_amdgcn_s_sleep(2);
            }
            vbuf[j0 + 0] = 1.0f / cf.x;
            vbuf[j0 + 1] = 1.0f / cf.y;
            vbuf[j0 + 2] = 1.0f / cf.z;
            vbuf[j0 + 3] = 1.0f / cf.w;
            __syncthreads();
            float a4 = 0.f, a5 = 0.f, a6 = 0.f, a7 = 0.f;
            #pragma unroll
            for (int k = 0; k < 16; ++k) {
                const int cc = 256 * k + 4 * l;
                U8 e; e.s = *(const ushort4*)(Eh + w * NN + cc);  // conflict-free
                float4 vv = *(const float4*)(vbuf + cc);          // conflict-free
                float2 f01 = __half22float2(e.h[0]);
                float2 f23 = __half22float2(e.h[1]);
                a4 = fmaf(f01.x, vv.x, a4);
                a5 = fmaf(f01.y, vv.y, a5);
                a6 = fmaf(f23.x, vv.z, a6);
                a7 = fmaf(f23.y, vv.w, a7);
            }
            float acc = (a4 + a5) + (a6 + a7);
            #pragma unroll
            for (int off = 32; off > 0; off >>= 1)
                acc += __shfl_xor(acc, off, 64);
            if (l == 0) { float r = 1.0f / acc; u_lds[w] = (double)r; uf_lds[w] = r; }
        } else {
            // t=19: fp64 colsums -> v; fp64-accum row pass (argmax-grade numerics)
            const int j0 = tid * 4;
            DF x, y;
            for (;;) {
                ld2_dev_d2(colD + j0, colD + j0 + 2, x.f, y.f);
                if (__all(x.d[0] > 0.0 && x.d[1] > 0.0 &&
                          y.d[0] > 0.0 && y.d[1] > 0.0)) break;
                __builtin_amdgcn_s_sleep(2);
            }
            vbuf[j0 + 0] = (float)(1.0 / x.d[0]);
            vbuf[j0 + 1] = (float)(1.0 / x.d[1]);
            vbuf[j0 + 2] = (float)(1.0 / y.d[0]);
            vbuf[j0 + 3] = (float)(1.0 / y.d[1]);
            __syncthreads();
            double a4 = 0, a5 = 0, a6 = 0, a7 = 0;
            #pragma unroll
            for (int k = 0; k < 16; ++k) {
                const int cc = 256 * k + 4 * l;
                U8 e; e.s = *(const ushort4*)(Eh + w * NN + cc);
                float4 vv = *(const float4*)(vbuf + cc);
                float2 f01 = __half22float2(e.h[0]);
                float2 f23 = __half22float2(e.h[1]);
                a4 = fma((double)f01.x, (double)vv.x, a4);
                a5 = fma((double)f01.y, (double)vv.y, a5);
                a6 = fma((double)f23.x, (double)vv.z, a6);
                a7 = fma((double)f23.y, (double)vv.w, a7);
            }
            double acc = (a4 + a5) + (a6 + a7);
            #pragma unroll
            for (int off = 32; off > 0; off >>= 1)
                acc += __shfl_xor(acc, off, 64);
            if (l == 0) u_lds[w] = 1.0 / acc;
        }
        __syncthreads();   // publish u for next C (block-local only)
    }

    // ---------- final: P = exp(W + lv + lu); H = one-hot(argmax(W + lv)) ----------
    double* lv = (double*)smem;                        // alias Eh (E no longer needed)
    {
        const int j0 = tid * 4;
        DF x, y;
        ld2_dev_d2(colD + j0, colD + j0 + 2, x.f, y.f);  // presence proven by R(19)
        lv[j0 + 0] = -log(x.d[0]);
        lv[j0 + 1] = -log(x.d[1]);
        lv[j0 + 2] = -log(y.d[0]);
        lv[j0 + 3] = -log(y.d[1]);
    }
    __syncthreads();
    {
        const size_t i = (size_t)(b * ROWS + w);
        const float2* wp = (const float2*)(W + i * NN) + l;
        float2* pp = (float2*)(P + i * NN) + l;
        float2* hp = (float2*)(H + i * NN) + l;
        const double lu = log(u_lds[w]);

        double besty = -1e300;
        int bestj = 0;
        #pragma unroll 4
        for (int k = 0; k < 32; ++k) {
            float2 x = wp[k * 64];                     // 8 B/lane, 512 B/wave coalesced
            int jb = k * 128 + l * 2;
            double2 lvv = *(const double2*)(lv + jb);  // 16 B/lane, conflict-free
            double y0 = (double)x.x + lvv.x;
            double y1 = (double)x.y + lvv.y;
            float2 pv;
            pv.x = expf((float)(y0 + lu));
            pv.y = expf((float)(y1 + lu));
            pp[k * 64] = pv;
            if (y0 > besty) { besty = y0; bestj = jb + 0; }   // strict > keeps first index
            if (y1 > besty) { besty = y1; bestj = jb + 1; }
        }
        for (int off = 32; off > 0; off >>= 1) {
            double oy = __shfl_xor(besty, off, 64);
            int    oj = __shfl_xor(bestj, off, 64);
            if (oy > besty || (oy == besty && oj < bestj)) { besty = oy; bestj = oj; }
        }
        #pragma unroll 4
        for (int k = 0; k < 32; ++k) {
            int jb = k * 128 + l * 2;
            float2 hv;
            hv.x = (jb + 0 == bestj) ? 1.0f : 0.0f;
            hv.y = (jb + 1 == bestj) ? 1.0f : 0.0f;
            hp[k * 64] = hv;
        }
    }
}

extern "C" void kernel_launch(void* const* d_in, const int* in_sizes, int n_in,
                              void* d_out, int out_size, void* d_ws, size_t ws_size,
                              hipStream_t stream) {
    const float* W = (const float*)d_in[0];
    float* P = (float*)d_out;                     // P_hat
    float* H = P + (size_t)NN * NN;               // P_hat_hard (one-hot numerically)

    float*  bufF  = (float*)d_ws;                          // 8 MiB
    double* partD = (double*)(bufF + 2 * (size_t)NBLK * NN);   // 8 MiB
    float*  colF  = (float*)(partD + (size_t)NBLK * NN);       // 320 KiB
    double* colD  = (double*)(colF + (size_t)NITER * NN);      // 32 KiB

    static bool attr_done = false;
    if (!attr_done) {
        (void)hipFuncSetAttribute((const void*)k_sink,
                                  hipFuncAttributeMaxDynamicSharedMemorySize,
                                  SMEM_BYTES);
        attr_done = true;
    }

    k_binit<<<(ZTOT + 255) / 256, 256, 0, stream>>>((float4*)d_ws);

    // Plain launch: no grid.sync in the kernel; co-residency structural (see above).
    k_sink<<<dim3(NBLK), dim3(TPB), SMEM_BYTES, stream>>>(
        W, P, H, bufF, partD, colF, colD);
}